// Round 3
// baseline (542.900 us; speedup 1.0000x reference)
//
#include <hip/hip_runtime.h>
#include <hip/hip_bf16.h>

// GAT layer: B=2, N=2048, C_IN=128, H=16, c=8.
// exp(lrelu(lp_i+lc_j) - m_i) = max(P1_i*Q1_j, P2_i*Q2_j), all <= 1.
// Round 3: attn waves slimmed to 4 i-rows (acc[4][8]) to fit 64 VGPRs ->
// 8 waves/SIMD (TLP replaces software prefetch); proj re-gridded for occupancy.
// d_out = [out: B*N*128][adj copy: B*N*N]

#define B_   2
#define N_   2048
#define CIN_ 128
#define H_   16
#define C_   8

__global__ __launch_bounds__(128) void proj_kernel(
    const float* __restrict__ nf, const float* __restrict__ W,
    const float* __restrict__ bias, const float* __restrict__ a,
    float* __restrict__ hT, float* __restrict__ lpT, float* __restrict__ lcT) {
  const int row0 = blockIdx.x * 2;       // 2 global rows (b*N+n) per block
  const int t    = threadIdx.x;          // output column 0..127
  __shared__ float sNf[2][CIN_];
  if (t < 64) {
    ((float4*)&sNf[0][0])[t] = ((const float4*)(nf + (long)row0 * CIN_))[t];
  }
  __syncthreads();
  float acc0 = bias[t], acc1 = acc0;
#pragma unroll 16
  for (int k = 0; k < CIN_; ++k) {
    const float w = W[k * 128 + t];
    acc0 = fmaf(sNf[0][k], w, acc0);
    acc1 = fmaf(sNf[1][k], w, acc1);
  }
  const int h = t >> 3, kc = t & 7;
  const float ap = a[h * 16 + kc], ac = a[h * 16 + 8 + kc];
  float accr[2] = {acc0, acc1};
#pragma unroll
  for (int r = 0; r < 2; ++r) {
    const int row = row0 + r;
    const int b = row >> 11, n = row & (N_ - 1);
    hT[((long)(b * H_ + h) * N_ + n) * C_ + kc] = accr[r];
    float lpv = accr[r] * ap, lcv = accr[r] * ac;
#pragma unroll
    for (int s = 1; s < 8; s <<= 1) {
      lpv += __shfl_xor(lpv, s);
      lcv += __shfl_xor(lcv, s);
    }
    if (kc == 0) {
      lpT[(long)(b * H_ + h) * N_ + n] = lpv;
      lcT[(long)(b * H_ + h) * N_ + n] = lcv;
    }
  }
}

__global__ __launch_bounds__(512, 8) void attn_kernel(
    const float* __restrict__ adj, const float* __restrict__ hT,
    const float* __restrict__ lpT, const float* __restrict__ lcT,
    float* __restrict__ out, float* __restrict__ adj_out) {
  const int hgroup = blockIdx.x & 1;     // which 8 heads
  const int tile   = blockIdx.x >> 1;
  const int b      = tile >> 9;          // 512 i-tiles per batch
  const int i0     = (tile & 511) * 4;
  const int tid    = threadIdx.x;
  const int wid    = tid >> 6;           // 0..7
  const int lane   = tid & 63;

  __shared__ float sAdj[4][N_];          // 32 KB -> 4 blocks/CU fit in 128 KB

  // Stage 4 adjacency rows; wave w does row w>>1, half w&1.
  // Fused adj copy to d_out (hgroup 0 only).
  {
    const int r = wid >> 1, half = wid & 1;
    const float4* arow = (const float4*)(adj + ((long)(b * N_ + i0 + r)) * N_);
    float4* orow = (float4*)(adj_out + ((long)(b * N_ + i0 + r)) * N_);
    float4* s4 = (float4*)(&sAdj[r][0]);
#pragma unroll
    for (int ch = 0; ch < 4; ++ch) {
      const int idx = half * 256 + ch * 64 + lane;
      const float4 v = arow[idx];
      s4[idx] = v;
      if (hgroup == 0) orow[idx] = v;
    }
  }
  __syncthreads();

  const int  hw   = hgroup * 8 + wid;    // this wave's head
  const long base = (long)(b * H_ + hw) * N_;
  const float* lcp = lcT + base;
  const float4* hp = (const float4*)(hT + base * C_);

  // Per-wave Lm = max_j lc (overflow-safety shift)
  float Lm = -1e30f;
#pragma unroll
  for (int k = 0; k < 32; ++k) Lm = fmaxf(Lm, lcp[k * 64 + lane]);
#pragma unroll
  for (int s = 1; s < 64; s <<= 1) Lm = fmaxf(Lm, __shfl_xor(Lm, s));

  float P1[4], P2[4], lrow[4], acc[4][8];
#pragma unroll
  for (int r = 0; r < 4; ++r) {
    const float lp = lpT[base + i0 + r];
    const float s0 = lp + Lm;
    const float mrow = fmaxf(s0, 0.2f * s0);   // lrelu(lp+Lm) >= row max logit
    P1[r] = __expf(s0 - mrow);
    P2[r] = __expf(0.2f * s0 - mrow);
    lrow[r] = 0.0f;
#pragma unroll
    for (int k = 0; k < 8; ++k) acc[r][k] = 0.0f;
  }

  for (int jj = 0; jj < 32; ++jj) {
    const int j = jj * 64 + lane;
    const float  lc = lcp[j];
    const float4 h0 = hp[j * 2];
    const float4 h1 = hp[j * 2 + 1];
    const float tq = lc - Lm;
    const float Q1 = __expf(tq);
    const float Q2 = __expf(0.2f * tq);
#pragma unroll
    for (int r = 0; r < 4; ++r) {
      const float e = fmaxf(P1[r] * Q1, P2[r] * Q2) * sAdj[r][j];
      lrow[r] += e;
      acc[r][0] = fmaf(e, h0.x, acc[r][0]);
      acc[r][1] = fmaf(e, h0.y, acc[r][1]);
      acc[r][2] = fmaf(e, h0.z, acc[r][2]);
      acc[r][3] = fmaf(e, h0.w, acc[r][3]);
      acc[r][4] = fmaf(e, h1.x, acc[r][4]);
      acc[r][5] = fmaf(e, h1.y, acc[r][5]);
      acc[r][6] = fmaf(e, h1.z, acc[r][6]);
      acc[r][7] = fmaf(e, h1.w, acc[r][7]);
    }
  }

  // Full 64-lane butterfly reduction.
#pragma unroll
  for (int s = 1; s < 64; s <<= 1) {
#pragma unroll
    for (int r = 0; r < 4; ++r) {
      lrow[r] += __shfl_xor(lrow[r], s);
#pragma unroll
      for (int k = 0; k < 8; ++k) acc[r][k] += __shfl_xor(acc[r][k], s);
    }
  }

  if (lane < 32) {
    const int rsel = lane >> 3, ksel = lane & 7;
    float av = 0.0f, lv = 1.0f;
#pragma unroll
    for (int r = 0; r < 4; ++r) {
      if (rsel == r) lv = lrow[r];
#pragma unroll
      for (int k = 0; k < 8; ++k)
        if (rsel == r && ksel == k) av = acc[r][k];
    }
    out[((long)(b * N_ + i0 + rsel)) * (H_ * C_) + hw * C_ + ksel] = av / lv;
  }
}

extern "C" void kernel_launch(void* const* d_in, const int* in_sizes, int n_in,
                              void* d_out, int out_size, void* d_ws, size_t ws_size,
                              hipStream_t stream) {
  const float* nf   = (const float*)d_in[0];
  const float* adj  = (const float*)d_in[1];
  const float* W    = (const float*)d_in[2];
  const float* bias = (const float*)d_in[3];
  const float* a    = (const float*)d_in[4];

  float* out     = (float*)d_out;
  float* adj_out = out + (long)B_ * N_ * H_ * C_;   // 524288 offset

  float* ws  = (float*)d_ws;
  float* hT  = ws;                        // B*H*N*C = 524288 floats
  float* lpT = ws + 524288;               // B*H*N   =  65536
  float* lcT = ws + 589824;               // B*H*N   =  65536

  hipLaunchKernelGGL(proj_kernel, dim3(B_ * N_ / 2), dim3(128), 0, stream,
                     nf, W, bias, a, hT, lpT, lcT);
  hipLaunchKernelGGL(attn_kernel, dim3(B_ * (N_ / 4) * 2), dim3(512), 0, stream,
                     adj, hT, lpT, lcT, out, adj_out);
}

// Round 4
// 161.325 us; speedup vs baseline: 3.3653x; 3.3653x over previous
//
#include <hip/hip_runtime.h>
#include <hip/hip_bf16.h>

// GAT layer: B=2, N=2048, C_IN=128, H=16, c=8.
// exp(lrelu(lp_i+lc_j)) = max(exp(lp)exp(lc), exp(0.2lp)exp(0.2lc))  -- exact,
// and |logits| << 88 so no softmax shift is needed (fp32 exp overflow-safe).
// Round 4: revert round-3's forced occupancy (it spilled: VGPR=32, WRITE 1.27GB);
// instead cut instructions with packed fp32 (v_pk_fma_f32 et al.) via float2
// ext-vectors: rows paired in the e-computation, features paired in the FMAs.
// d_out = [out: B*N*128][adj copy: B*N*N]

#define B_   2
#define N_   2048
#define CIN_ 128
#define H_   16
#define C_   8

typedef float v2f __attribute__((ext_vector_type(2)));

__global__ __launch_bounds__(128) void proj_kernel(
    const float* __restrict__ nf, const float* __restrict__ W,
    const float* __restrict__ bias, const float* __restrict__ a,
    float* __restrict__ hT, float* __restrict__ lpT, float* __restrict__ lcT) {
  const int row0 = blockIdx.x * 2;       // 2 global rows (b*N+n) per block
  const int t    = threadIdx.x;          // output column 0..127
  __shared__ float sNf[2][CIN_];
  if (t < 64) {
    ((float4*)&sNf[0][0])[t] = ((const float4*)(nf + (long)row0 * CIN_))[t];
  }
  __syncthreads();
  float acc0 = bias[t], acc1 = acc0;
#pragma unroll 16
  for (int k = 0; k < CIN_; ++k) {
    const float w = W[k * 128 + t];
    acc0 = fmaf(sNf[0][k], w, acc0);
    acc1 = fmaf(sNf[1][k], w, acc1);
  }
  const int h = t >> 3, kc = t & 7;
  const float ap = a[h * 16 + kc], ac = a[h * 16 + 8 + kc];
  float accr[2] = {acc0, acc1};
#pragma unroll
  for (int r = 0; r < 2; ++r) {
    const int row = row0 + r;
    const int b = row >> 11, n = row & (N_ - 1);
    hT[((long)(b * H_ + h) * N_ + n) * C_ + kc] = accr[r];
    float lpv = accr[r] * ap, lcv = accr[r] * ac;
#pragma unroll
    for (int s = 1; s < 8; s <<= 1) {
      lpv += __shfl_xor(lpv, s);
      lcv += __shfl_xor(lcv, s);
    }
    if (kc == 0) {
      lpT[(long)(b * H_ + h) * N_ + n] = lpv;
      lcT[(long)(b * H_ + h) * N_ + n] = lcv;
    }
  }
}

__global__ __launch_bounds__(512) void attn_kernel(
    const float* __restrict__ adj, const float* __restrict__ hT,
    const float* __restrict__ lpT, const float* __restrict__ lcT,
    float* __restrict__ out, float* __restrict__ adj_out) {
  const int hgroup = blockIdx.x & 1;     // which 8 heads
  const int tile   = blockIdx.x >> 1;
  const int b      = tile >> 8;          // 256 i-tiles per batch
  const int i0     = (tile & 255) * 8;
  const int tid    = threadIdx.x;
  const int wid    = tid >> 6;           // 0..7
  const int lane   = tid & 63;

  __shared__ float sAdj[8][N_];          // 64 KB: adjacency rows as floats

  // Stage adjacency rows (float4) + fused adj copy to d_out (hgroup 0 only).
  {
    const float4* arow = (const float4*)(adj + ((long)(b * N_ + i0 + wid)) * N_);
    float4* orow = (float4*)(adj_out + ((long)(b * N_ + i0 + wid)) * N_);
    float4* lrow4 = (float4*)(&sAdj[wid][0]);
#pragma unroll
    for (int ch = 0; ch < 8; ++ch) {
      const int idx = ch * 64 + lane;    // float4 index 0..511
      const float4 v = arow[idx];
      lrow4[idx] = v;
      if (hgroup == 0) orow[idx] = v;
    }
  }
  __syncthreads();

  const int  hw   = hgroup * 8 + wid;    // this wave's head
  const long base = (long)(b * H_ + hw) * N_;
  const float* lcp = lcT + base;
  const float4* hp = (const float4*)(hT + base * C_);

  // Row pairs: P1[p] = (exp(lp_{2p}), exp(lp_{2p+1})), P2 = same with 0.2x.
  v2f P1[4], P2[4], lrow[4], acc[8][4];
#pragma unroll
  for (int p = 0; p < 4; ++p) {
    const float lp0 = lpT[base + i0 + 2 * p];
    const float lp1 = lpT[base + i0 + 2 * p + 1];
    P1[p] = (v2f){__expf(lp0), __expf(lp1)};
    P2[p] = (v2f){__expf(0.2f * lp0), __expf(0.2f * lp1)};
    lrow[p] = 0.0f;
#pragma unroll
    for (int k = 0; k < 4; ++k) { acc[2 * p][k] = 0.0f; acc[2 * p + 1][k] = 0.0f; }
  }

  // Prefetched j-loop. Per j: Q uniform-per-lane; rows paired for e-comp,
  // features paired for the accumulate FMAs (v_pk_fma_f32 targets).
  float  lc_c = lcp[lane];
  float4 h0_c = hp[lane * 2];
  float4 h1_c = hp[lane * 2 + 1];
  for (int jj = 0; jj < 32; ++jj) {
    const int jn = ((jj + 1) & 31) * 64 + lane;   // next chunk (wraps harmlessly)
    const float  lc_n = lcp[jn];
    const float4 h0_n = hp[jn * 2];
    const float4 h1_n = hp[jn * 2 + 1];
    const int j = jj * 64 + lane;

    const v2f Q1 = __expf(lc_c);           // splat
    const v2f Q2 = __expf(0.2f * lc_c);    // splat
    const v2f hv0 = (v2f){h0_c.x, h0_c.y};
    const v2f hv1 = (v2f){h0_c.z, h0_c.w};
    const v2f hv2 = (v2f){h1_c.x, h1_c.y};
    const v2f hv3 = (v2f){h1_c.z, h1_c.w};

#pragma unroll
    for (int p = 0; p < 4; ++p) {
      const v2f av = (v2f){sAdj[2 * p][j], sAdj[2 * p + 1][j]};
      const v2f e2 = __builtin_elementwise_max(P1[p] * Q1, P2[p] * Q2) * av;
      lrow[p] += e2;
      const v2f e0 = e2.x;                 // splat row 2p
      const v2f e1 = e2.y;                 // splat row 2p+1
      acc[2 * p][0]     = __builtin_elementwise_fma(e0, hv0, acc[2 * p][0]);
      acc[2 * p][1]     = __builtin_elementwise_fma(e0, hv1, acc[2 * p][1]);
      acc[2 * p][2]     = __builtin_elementwise_fma(e0, hv2, acc[2 * p][2]);
      acc[2 * p][3]     = __builtin_elementwise_fma(e0, hv3, acc[2 * p][3]);
      acc[2 * p + 1][0] = __builtin_elementwise_fma(e1, hv0, acc[2 * p + 1][0]);
      acc[2 * p + 1][1] = __builtin_elementwise_fma(e1, hv1, acc[2 * p + 1][1]);
      acc[2 * p + 1][2] = __builtin_elementwise_fma(e1, hv2, acc[2 * p + 1][2]);
      acc[2 * p + 1][3] = __builtin_elementwise_fma(e1, hv3, acc[2 * p + 1][3]);
    }
    lc_c = lc_n; h0_c = h0_n; h1_c = h1_n;
  }

  // Full 64-lane butterfly reduction (component-wise).
#pragma unroll
  for (int s = 1; s < 64; s <<= 1) {
#pragma unroll
    for (int p = 0; p < 4; ++p) {
      lrow[p].x += __shfl_xor(lrow[p].x, s);
      lrow[p].y += __shfl_xor(lrow[p].y, s);
    }
#pragma unroll
    for (int r = 0; r < 8; ++r)
#pragma unroll
      for (int k = 0; k < 4; ++k) {
        acc[r][k].x += __shfl_xor(acc[r][k].x, s);
        acc[r][k].y += __shfl_xor(acc[r][k].y, s);
      }
  }

  // lane -> (row rsel, feature ksel); all 64 lanes write one output each.
  const int rsel = lane >> 3, ksel = lane & 7;
  float av = 0.0f, lv = 1.0f;
#pragma unroll
  for (int p = 0; p < 4; ++p) {
    if (rsel == 2 * p)     lv = lrow[p].x;
    if (rsel == 2 * p + 1) lv = lrow[p].y;
#pragma unroll
    for (int k = 0; k < 4; ++k) {
      if (rsel == 2 * p     && ksel == 2 * k)     av = acc[2 * p][k].x;
      if (rsel == 2 * p     && ksel == 2 * k + 1) av = acc[2 * p][k].y;
      if (rsel == 2 * p + 1 && ksel == 2 * k)     av = acc[2 * p + 1][k].x;
      if (rsel == 2 * p + 1 && ksel == 2 * k + 1) av = acc[2 * p + 1][k].y;
    }
  }
  out[((long)(b * N_ + i0 + rsel)) * (H_ * C_) + hw * C_ + ksel] = av / lv;
}

extern "C" void kernel_launch(void* const* d_in, const int* in_sizes, int n_in,
                              void* d_out, int out_size, void* d_ws, size_t ws_size,
                              hipStream_t stream) {
  const float* nf   = (const float*)d_in[0];
  const float* adj  = (const float*)d_in[1];
  const float* W    = (const float*)d_in[2];
  const float* bias = (const float*)d_in[3];
  const float* a    = (const float*)d_in[4];

  float* out     = (float*)d_out;
  float* adj_out = out + (long)B_ * N_ * H_ * C_;   // 524288 offset

  float* ws  = (float*)d_ws;
  float* hT  = ws;                        // B*H*N*C = 524288 floats
  float* lpT = ws + 524288;               // B*H*N   =  65536
  float* lcT = ws + 589824;               // B*H*N   =  65536

  hipLaunchKernelGGL(proj_kernel, dim3(B_ * N_ / 2), dim3(128), 0, stream,
                     nf, W, bias, a, hT, lpT, lcT);
  hipLaunchKernelGGL(attn_kernel, dim3(B_ * (N_ / 8) * 2), dim3(512), 0, stream,
                     adj, hT, lpT, lcT, out, adj_out);
}